// Round 7
// baseline (162.319 us; speedup 1.0000x reference)
//
#include <hip/hip_runtime.h>
#include <cstdint>

typedef __bf16 bf16_t;
typedef bf16_t bf16x4 __attribute__((ext_vector_type(4)));
typedef bf16_t bf16x8 __attribute__((ext_vector_type(8)));
typedef float f32x4 __attribute__((ext_vector_type(4)));

#define GLD_LDS16(g, l)                                                        \
  __builtin_amdgcn_global_load_lds(                                            \
      (const __attribute__((address_space(1))) void*)(g),                      \
      (__attribute__((address_space(3))) void*)(l), 16, 0, 0)

#define LOG2E 1.44269504088896340736f
#define SBAR() __builtin_amdgcn_sched_barrier(0)

static __device__ __forceinline__ void wait_vm4() {
  asm volatile("s_waitcnt vmcnt(4)" ::: "memory");
}
static __device__ __forceinline__ void wait_vm0() {
  asm volatile("s_waitcnt vmcnt(0)" ::: "memory");
}

static __device__ __forceinline__ unsigned short bf16_bits(float f) {
  bf16_t h = (bf16_t)f;
  return __builtin_bit_cast(unsigned short, h);
}

// ---- fused prep: fp32->bf16 convert (x,y) + weight transpose-convert ------
__global__ void prep_kernel(const float* __restrict__ x,
                            const float* __restrict__ y,
                            const float* __restrict__ Wq,
                            const float* __restrict__ Wk,
                            const float* __restrict__ Wv,
                            const float* __restrict__ Wo,
                            bf16_t* __restrict__ xb, bf16_t* __restrict__ yb,
                            bf16_t* __restrict__ WqT,
                            bf16_t* __restrict__ WkvT,
                            bf16_t* __restrict__ WoT) {
  __shared__ float tile[32][33];
  int bid = blockIdx.x;
  if (bid < 6144) {
    int i = bid * 256 + threadIdx.x;
    const float* src;
    bf16_t* dst;
    if (i < 524288) { src = x; dst = xb; }
    else            { src = y; dst = yb; i -= 524288; }
    const float4* s = (const float4*)src;
    float4 a = s[i * 2];
    float4 b = s[i * 2 + 1];
    bf16x8 o;
    o[0] = (bf16_t)a.x; o[1] = (bf16_t)a.y; o[2] = (bf16_t)a.z; o[3] = (bf16_t)a.w;
    o[4] = (bf16_t)b.x; o[5] = (bf16_t)b.y; o[6] = (bf16_t)b.z; o[7] = (bf16_t)b.w;
    *(bf16x8*)(dst + (size_t)i * 8) = o;
    return;
  }
  bid -= 6144;
  const float* src; bf16_t* dst; int R, lb;
  if (bid < 1024)      { src = Wq; dst = WqT;                        R = 1024; lb = bid; }
  else if (bid < 3072) { src = Wk; dst = WkvT;                       R = 2048; lb = bid - 1024; }
  else if (bid < 5120) { src = Wv; dst = WkvT + (size_t)1024 * 2048; R = 2048; lb = bid - 3072; }
  else                 { src = Wo; dst = WoT;                        R = 1024; lb = bid - 5120; }
  int c0 = (lb & 31) << 5, r0 = (lb >> 5) << 5;
  int tc = threadIdx.x & 31, tr = threadIdx.x >> 5;  // tr in 0..7
#pragma unroll
  for (int i = 0; i < 4; i++)
    tile[tr + i * 8][tc] = src[(size_t)(r0 + tr + i * 8) * 1024 + c0 + tc];
  __syncthreads();
#pragma unroll
  for (int i = 0; i < 4; i++)
    dst[(size_t)(c0 + tr + i * 8) * R + r0 + tc] = (bf16_t)tile[tc][tr + i * 8];
}

// ======== fused Q+KV projection: 256x256 tile, 8 waves (2Mx4N), BK=32 ======
// 3 LDS buffers (96KB), depth-2 prefetch, counted vmcnt(4) (never drains to 0
// in the main loop). Per K-tile: 2 phases, each = {stage half of tile t+2 |
// 4-6 ds_read_b128 | 16 MFMA}. Swizzle: 64B rows of 4x16B slots, LDS slot s
// holds global slot s ^ ((row>>1)&3); staged via pre-swizzled global source,
// read with the same XOR -> 2-way (free) bank access.
// Blocks 0..63: Q-proj (M=4096,N=1024,K=1024); 64..191: KV (N=2048,K=2048).
__global__ __launch_bounds__(512, 2) void qkv_kernel(
    const bf16_t* __restrict__ xbp, const bf16_t* __restrict__ ybp,
    const bf16_t* __restrict__ WqT, const bf16_t* __restrict__ WkvT,
    bf16_t* __restrict__ Qb, bf16_t* __restrict__ Kb,
    bf16_t* __restrict__ VTb) {
  __shared__ bf16_t As[3][256 * 32];
  __shared__ bf16_t Bs[3][256 * 32];
  const int t = threadIdx.x, w = t >> 6, l = t & 63;
  const int l15 = l & 15, l4 = l >> 4;
  const int wr = w >> 2, wc = w & 3;  // 2M x 4N waves
  const bool isQ = blockIdx.x < 64;
  const int i = isQ ? blockIdx.x : blockIdx.x - 64;
  const int ybt = (i & 7) * 2 + ((i >> 3) & 1);  // A-panel pair per XCD
  const int xbt = i >> 4;
  const int m0 = ybt * 256, n0 = xbt * 256;
  const bf16_t* A0 = isQ ? xbp : ybp;
  const bf16_t* A1 = isQ ? xbp : ybp + (size_t)4096 * 1024;
  const int Ksplit = 1024;
  const bf16_t* BT = isQ ? WqT : WkvT;
  const int Ktot = isQ ? 1024 : 2048;
  const int nkt = Ktot >> 5;

  f32x4 acc[8][4] = {};

  // fragment read offsets (elements), swizzled
  int offA[8], offB[4];
#pragma unroll
  for (int mi = 0; mi < 8; mi++) {
    int row = wr * 128 + mi * 16 + l15;
    offA[mi] = row * 32 + (l4 ^ ((row >> 1) & 3)) * 8;
  }
#pragma unroll
  for (int ni = 0; ni < 4; ni++) {
    int row = wc * 64 + ni * 16 + l15;
    offB[ni] = row * 32 + (l4 ^ ((row >> 1) & 3)) * 8;
  }

#define ST_A(buf, kt)                                                          \
  {                                                                            \
    const int kbase = (kt) * 32;                                               \
    _Pragma("unroll") for (int j = 0; j < 2; j++) {                            \
      int c = (j * 8 + w) * 64 + l;                                            \
      int row = c >> 2;                                                        \
      int ks = ((c & 3) ^ ((row >> 1) & 3)) * 8;                               \
      int kg = kbase + ks;                                                     \
      const bf16_t* s = (kg < Ksplit)                                          \
                            ? (A0 + (size_t)(m0 + row) * 1024 + kg)            \
                            : (A1 + (size_t)(m0 + row) * 1024 + (kg - Ksplit));\
      GLD_LDS16(s, As[buf] + c * 8);                                           \
    }                                                                          \
  }
#define ST_B(buf, kt)                                                          \
  {                                                                            \
    const int kbase = (kt) * 32;                                               \
    _Pragma("unroll") for (int j = 0; j < 2; j++) {                            \
      int c = (j * 8 + w) * 64 + l;                                            \
      int row = c >> 2;                                                        \
      int ks = ((c & 3) ^ ((row >> 1) & 3)) * 8;                               \
      const bf16_t* s = BT + (size_t)(n0 + row) * Ktot + kbase + ks;           \
      GLD_LDS16(s, Bs[buf] + c * 8);                                           \
    }                                                                          \
  }

  ST_A(0, 0); ST_B(0, 0);
  ST_A(1, 1); ST_B(1, 1);
  wait_vm4();
  SBAR();
  __builtin_amdgcn_s_barrier();

  int cur = 0;
  for (int kt = 0; kt < nkt; ++kt) {
    int nx2 = cur + 2; if (nx2 >= 3) nx2 -= 3;
    const bool more = (kt + 2 < nkt);
    bf16x8 bfr[4], af[4];
    // ---- phase 0: stage A(t+2) | read B + A(mi 0..3) | 16 MFMA ----
    if (more) ST_A(nx2, kt + 2);
#pragma unroll
    for (int ni = 0; ni < 4; ni++)
      bfr[ni] = *(const bf16x8*)&Bs[cur][offB[ni]];
#pragma unroll
    for (int mi = 0; mi < 4; mi++)
      af[mi] = *(const bf16x8*)&As[cur][offA[mi]];
    __builtin_amdgcn_s_setprio(1);
#pragma unroll
    for (int mi = 0; mi < 4; mi++)
#pragma unroll
      for (int ni = 0; ni < 4; ni++)
        acc[mi][ni] = __builtin_amdgcn_mfma_f32_16x16x32_bf16(
            af[mi], bfr[ni], acc[mi][ni], 0, 0, 0);
    __builtin_amdgcn_s_setprio(0);
    __builtin_amdgcn_s_barrier();
    // ---- phase 1: stage B(t+2) | read A(mi 4..7) | 16 MFMA ----
    if (more) ST_B(nx2, kt + 2);
#pragma unroll
    for (int mi = 0; mi < 4; mi++)
      af[mi] = *(const bf16x8*)&As[cur][offA[mi + 4]];
    __builtin_amdgcn_s_setprio(1);
#pragma unroll
    for (int mi = 0; mi < 4; mi++)
#pragma unroll
      for (int ni = 0; ni < 4; ni++)
        acc[mi + 4][ni] = __builtin_amdgcn_mfma_f32_16x16x32_bf16(
            af[mi], bfr[ni], acc[mi + 4][ni], 0, 0, 0);
    __builtin_amdgcn_s_setprio(0);
    if (more) wait_vm4(); else wait_vm0();
    SBAR();
    __builtin_amdgcn_s_barrier();
    cur = (cur == 2) ? 0 : cur + 1;
  }
#undef ST_A
#undef ST_B

  // ---- epilogue ----
#pragma unroll
  for (int mi = 0; mi < 8; mi++) {
#pragma unroll
    for (int ni = 0; ni < 4; ni++) {
      const int rbase = m0 + wr * 128 + mi * 16 + l4 * 4;
      const int col = n0 + wc * 64 + ni * 16 + l15;
      if (isQ) {
#pragma unroll
        for (int rr = 0; rr < 4; rr++)
          Qb[(size_t)(rbase + rr) * 1024 + col] =
              (bf16_t)(acc[mi][ni][rr] * (0.125f * LOG2E));
      } else if (n0 < 1024) {
#pragma unroll
        for (int rr = 0; rr < 4; rr++)
          Kb[(size_t)(rbase + rr) * 1024 + col] = (bf16_t)acc[mi][ni][rr];
      } else {
        union { unsigned short u[4]; uint2 v; } pk;
#pragma unroll
        for (int rr = 0; rr < 4; rr++)
          pk.u[rr] = bf16_bits(acc[mi][ni][rr]);
        *(uint2*)&VTb[(size_t)(col - 1024) * 4096 + rbase] = pk.v;
      }
    }
  }
}

// ---- O-proj: out(fp32) = ctx * WoT^T (128x128, 2-buffer, round-5 form) ----
__global__ __launch_bounds__(256, 2) void gemm_o(const bf16_t* __restrict__ A0,
                                                 const bf16_t* __restrict__ BT,
                                                 float* __restrict__ Cp) {
  __shared__ bf16_t As[2][128 * 32];
  __shared__ bf16_t Bs[2][128 * 32];
  const int t = threadIdx.x, w = t >> 6, l = t & 63;
  const int l15 = l & 15, l4 = l >> 4;
  const int wr = w >> 1, wc = w & 1;
  const int c0 = t, c1 = t + 256;
  const int ar0 = c0 >> 2, ar1 = c1 >> 2;
  const int ak0 = ((c0 & 3) ^ ((ar0 >> 1) & 3)) * 8;
  const int ak1 = ((c1 & 3) ^ ((ar1 >> 1) & 3)) * 8;
  int offA[4], offB[4];
#pragma unroll
  for (int mi = 0; mi < 4; mi++) {
    int rA = wr * 64 + mi * 16 + l15;
    offA[mi] = rA * 32 + (l4 ^ ((rA >> 1) & 3)) * 8;
    int rB = wc * 64 + mi * 16 + l15;
    offB[mi] = rB * 32 + (l4 ^ ((rB >> 1) & 3)) * 8;
  }
  const int i = blockIdx.x;
  const int ybt = (i & 7) * 4 + ((i >> 3) & 3);
  const int xbt = i >> 5;
  const int m0 = ybt * 128, n0 = xbt * 128;
  const int nkt = 32;
  f32x4 acc[4][4] = {};

#define OST(buf, kt)                                                           \
  {                                                                            \
    const int kbase = (kt) * 32;                                               \
    const bf16_t* s0 = A0 + (size_t)(m0 + ar0) * 1024 + kbase + ak0;           \
    GLD_LDS16(s0, As[buf] + c0 * 8);                                           \
    const bf16_t* s1 = A0 + (size_t)(m0 + ar1) * 1024 + kbase + ak1;           \
    GLD_LDS16(s1, As[buf] + c1 * 8);                                           \
    const bf16_t* b0 = BT + (size_t)(n0 + ar0) * 1024 + kbase + ak0;           \
    GLD_LDS16(b0, Bs[buf] + c0 * 8);                                           \
    const bf16_t* b1 = BT + (size_t)(n0 + ar1) * 1024 + kbase + ak1;           \
    GLD_LDS16(b1, Bs[buf] + c1 * 8);                                           \
  }

  OST(0, 0);
  __syncthreads();
  int cur = 0;
  for (int kt = 0; kt < nkt; ++kt) {
    if (kt + 1 < nkt) OST(cur ^ 1, kt + 1);
    bf16x8 af[4], bfr[4];
#pragma unroll
    for (int mi = 0; mi < 4; mi++)
      af[mi] = *(const bf16x8*)&As[cur][offA[mi]];
#pragma unroll
    for (int ni = 0; ni < 4; ni++)
      bfr[ni] = *(const bf16x8*)&Bs[cur][offB[ni]];
#pragma unroll
    for (int mi = 0; mi < 4; mi++)
#pragma unroll
      for (int ni = 0; ni < 4; ni++)
        acc[mi][ni] = __builtin_amdgcn_mfma_f32_16x16x32_bf16(
            af[mi], bfr[ni], acc[mi][ni], 0, 0, 0);
    __syncthreads();
    cur ^= 1;
  }
#undef OST

#pragma unroll
  for (int mi = 0; mi < 4; mi++) {
#pragma unroll
    for (int ni = 0; ni < 4; ni++) {
      const int rbase = m0 + wr * 64 + mi * 16 + l4 * 4;
      const int col = n0 + wc * 64 + ni * 16 + l15;
#pragma unroll
      for (int rr = 0; rr < 4; rr++)
        Cp[(size_t)(rbase + rr) * 1024 + col] = acc[mi][ni][rr];
    }
  }
}

// ---------------- flash attention, swapped-softmax --------------------------
__global__ __launch_bounds__(256, 4) void attn_kernel(
    const bf16_t* __restrict__ Q, const bf16_t* __restrict__ K,
    const bf16_t* __restrict__ VT, const float* __restrict__ bias,
    bf16_t* __restrict__ ctx) {
  __shared__ bf16_t Ks[2][64 * 64];
  __shared__ bf16_t Vs[2][64 * 64];
  __shared__ bf16_t Ps[4][1024];  // per-wave P^T: [khi(8)][q(16)][klo(8)]
  const int t = threadIdx.x, w = t >> 6, l = t & 63;
  const int l15 = l & 15, l4 = l >> 4;
  const int id = blockIdx.x;
  const int bh = id & 63, qt = id >> 6;
  const int b = bh >> 4, h = bh & 15;

  bf16x8 qf[2];
  {
    const bf16_t* Qb =
        Q + (size_t)(b * 1024 + qt * 64 + w * 16 + l15) * 1024 + h * 64;
#pragma unroll
    for (int ks = 0; ks < 2; ks++)
      qf[ks] = *(const bf16x8*)&Qb[ks * 32 + l4 * 8];
  }

#define ATTN_STAGE(buf, kt)                                                    \
  {                                                                            \
    _Pragma("unroll") for (int j = 0; j < 2; j++) {                            \
      int c = t + j * 256;                                                     \
      int row = c >> 3, sl = (c & 7) ^ (row & 7);                              \
      const bf16_t* srck =                                                     \
          K + (size_t)(b * 1024 + (kt) * 64 + row) * 1024 + h * 64 + sl * 8;   \
      GLD_LDS16(srck, Ks[buf] + c * 8);                                        \
      const bf16_t* srcv =                                                     \
          VT + (size_t)(h * 64 + row) * 4096 + b * 1024 + (kt) * 64 + sl * 8;  \
      GLD_LDS16(srcv, Vs[buf] + c * 8);                                        \
    }                                                                          \
  }

  float mrun = -INFINITY, lrun = 0.f;
  f32x4 ctxacc[4] = {};  // ctx^T: d=ni*16+l4*4+rr, q=w*16+l15

  ATTN_STAGE(0, 0);
  __syncthreads();
  int cur = 0;
  for (int kt = 0; kt < 16; ++kt) {
    if (kt + 1 < 16) ATTN_STAGE(cur ^ 1, kt + 1);

    f32x4 sacc[4] = {};
#pragma unroll
    for (int ks = 0; ks < 2; ks++) {
#pragma unroll
      for (int ni = 0; ni < 4; ni++) {
        int krow = ni * 16 + l15;
        int eoff = (krow * 64 + ks * 32 + l4 * 8) ^ ((krow & 7) << 3);
        bf16x8 kf = *(const bf16x8*)&Ks[cur][eoff];
        sacc[ni] = __builtin_amdgcn_mfma_f32_16x16x32_bf16(kf, qf[ks],
                                                           sacc[ni], 0, 0, 0);
      }
    }
#pragma unroll
    for (int ni = 0; ni < 4; ni++) {
      float4 bb =
          *(const float4*)&bias[b * 1024 + kt * 64 + ni * 16 + l4 * 4];
      sacc[ni][0] += (2.0f * LOG2E) * bb.x;
      sacc[ni][1] += (2.0f * LOG2E) * bb.y;
      sacc[ni][2] += (2.0f * LOG2E) * bb.z;
      sacc[ni][3] += (2.0f * LOG2E) * bb.w;
    }
    float tm = -INFINITY;
#pragma unroll
    for (int ni = 0; ni < 4; ni++)
#pragma unroll
      for (int rr = 0; rr < 4; rr++) tm = fmaxf(tm, sacc[ni][rr]);
    tm = fmaxf(tm, __shfl_xor(tm, 16));
    tm = fmaxf(tm, __shfl_xor(tm, 32));
    float mnew = fmaxf(mrun, tm);
    float sc = exp2f(mrun - mnew);
    float rsum = 0.f;
#pragma unroll
    for (int ni = 0; ni < 4; ni++) {
      bf16x4 pk;
#pragma unroll
      for (int rr = 0; rr < 4; rr++) {
        float p = exp2f(sacc[ni][rr] - mnew);
        rsum += p;
        pk[rr] = (bf16_t)p;
      }
      *(bf16x4*)&Ps[w][(ni * 2 + (l4 >> 1)) * 128 + l15 * 8 + (l4 & 1) * 4] =
          pk;
    }
    rsum += __shfl_xor(rsum, 16);
    rsum += __shfl_xor(rsum, 32);
    lrun = lrun * sc + rsum;
    mrun = mnew;
#pragma unroll
    for (int ni = 0; ni < 4; ni++) ctxacc[ni] *= sc;
#pragma unroll
    for (int kk = 0; kk < 2; kk++) {
      bf16x8 pf = *(const bf16x8*)&Ps[w][(kk * 4 + l4) * 128 + l15 * 8];
#pragma unroll
      for (int ni = 0; ni < 4; ni++) {
        int drow = ni * 16 + l15;
        int voff = (drow * 64 + kk * 32 + l4 * 8) ^ ((drow & 7) << 3);
        bf16x8 vf = *(const bf16x8*)&Vs[cur][voff];
        ctxacc[ni] = __builtin_amdgcn_mfma_f32_16x16x32_bf16(vf, pf, ctxacc[ni],
                                                             0, 0, 0);
      }
    }
    __syncthreads();
    cur ^= 1;
  }

  // epilogue: ctx^T -> LDS transpose (swizzled) -> coalesced bf16x8 stores
  bf16_t* T = Ks[0];  // 64q x 64d
  {
    float inv = 1.0f / lrun;
    int q = w * 16 + l15;
#pragma unroll
    for (int ni = 0; ni < 4; ni++) {
      bf16x4 tv;
#pragma unroll
      for (int rr = 0; rr < 4; rr++) tv[rr] = (bf16_t)(ctxacc[ni][rr] * inv);
      int d0 = ni * 16 + l4 * 4;
      *(bf16x4*)&T[q * 64 + (d0 ^ ((l15 & 7) << 3))] = tv;
    }
  }
  __syncthreads();
#pragma unroll
  for (int c = t; c < 512; c += 256) {
    int row = c >> 3, col8 = c & 7;
    bf16x8 v = *(const bf16x8*)&T[row * 64 + ((col8 * 8) ^ ((row & 7) << 3))];
    *(bf16x8*)&ctx[(size_t)(b * 1024 + qt * 64 + row) * 1024 + h * 64 +
                   col8 * 8] = v;
  }
#undef ATTN_STAGE
}

extern "C" void kernel_launch(void* const* d_in, const int* in_sizes, int n_in,
                              void* d_out, int out_size, void* d_ws,
                              size_t ws_size, hipStream_t stream) {
  const float* x = (const float*)d_in[0];    // [4,1024,1024]
  const float* y = (const float*)d_in[1];    // [2,4,1024,1024]
  const float* bias = (const float*)d_in[2]; // [4,1,1,1024]
  const float* Wq = (const float*)d_in[3];   // [1024,1024]
  const float* Wk = (const float*)d_in[4];   // [2,1024,1024]
  const float* Wv = (const float*)d_in[5];
  const float* Wo = (const float*)d_in[6];
  float* out = (float*)d_out;                // [4,1024,1024] fp32

  char* ws = (char*)d_ws;
  const size_t MB = 1024 * 1024;
  bf16_t* xb   = (bf16_t*)(ws + 0 * MB);    // 8MB
  bf16_t* yb   = (bf16_t*)(ws + 8 * MB);    // 16MB
  bf16_t* WqT  = (bf16_t*)(ws + 24 * MB);   // 2MB
  bf16_t* WkvT = (bf16_t*)(ws + 26 * MB);   // 8MB  [2048 n][2048 k]
  bf16_t* WoT  = (bf16_t*)(ws + 34 * MB);   // 2MB
  bf16_t* Qb   = (bf16_t*)(ws + 36 * MB);   // 8MB  (pre-scaled d^-.5*log2e)
  bf16_t* Kb   = (bf16_t*)(ws + 44 * MB);   // 8MB
  bf16_t* VTb  = (bf16_t*)(ws + 52 * MB);   // 8MB  [1024 d][4096 q]
  bf16_t* ctxb = (bf16_t*)(ws + 60 * MB);   // 8MB

  prep_kernel<<<12288, 256, 0, stream>>>(x, y, Wq, Wk, Wv, Wo, xb, yb, WqT,
                                         WkvT, WoT);
  // Q-proj (blocks 0..63) + KV-proj (blocks 64..191), 256^2 tiles, 512 thr
  qkv_kernel<<<192, 512, 0, stream>>>(xb, yb, WqT, WkvT, Qb, Kb, VTb);
  attn_kernel<<<1024, 256, 0, stream>>>(Qb, Kb, VTb, bias, ctxb);
  gemm_o<<<256, 256, 0, stream>>>(ctxb, WoT, out);
}

// Round 8
// 141.558 us; speedup vs baseline: 1.1467x; 1.1467x over previous
//
#include <hip/hip_runtime.h>
#include <cstdint>

typedef __bf16 bf16_t;
typedef bf16_t bf16x4 __attribute__((ext_vector_type(4)));
typedef bf16_t bf16x8 __attribute__((ext_vector_type(8)));
typedef float f32x4 __attribute__((ext_vector_type(4)));
typedef float f32x16 __attribute__((ext_vector_type(16)));

#define GLD_LDS16(g, l)                                                        \
  __builtin_amdgcn_global_load_lds(                                            \
      (const __attribute__((address_space(1))) void*)(g),                      \
      (__attribute__((address_space(3))) void*)(l), 16, 0, 0)

#define LOG2E 1.44269504088896340736f

static __device__ __forceinline__ unsigned short bf16_bits(float f) {
  bf16_t h = (bf16_t)f;
  return __builtin_bit_cast(unsigned short, h);
}

// ---- fused prep: fp32->bf16 convert (x,y) + weight transpose-convert ------
__global__ void prep_kernel(const float* __restrict__ x,
                            const float* __restrict__ y,
                            const float* __restrict__ Wq,
                            const float* __restrict__ Wk,
                            const float* __restrict__ Wv,
                            const float* __restrict__ Wo,
                            bf16_t* __restrict__ xb, bf16_t* __restrict__ yb,
                            bf16_t* __restrict__ WqT,
                            bf16_t* __restrict__ WkvT,
                            bf16_t* __restrict__ WoT) {
  __shared__ float tile[32][33];
  int bid = blockIdx.x;
  if (bid < 6144) {
    int i = bid * 256 + threadIdx.x;
    const float* src;
    bf16_t* dst;
    if (i < 524288) { src = x; dst = xb; }
    else            { src = y; dst = yb; i -= 524288; }
    const float4* s = (const float4*)src;
    float4 a = s[i * 2];
    float4 b = s[i * 2 + 1];
    bf16x8 o;
    o[0] = (bf16_t)a.x; o[1] = (bf16_t)a.y; o[2] = (bf16_t)a.z; o[3] = (bf16_t)a.w;
    o[4] = (bf16_t)b.x; o[5] = (bf16_t)b.y; o[6] = (bf16_t)b.z; o[7] = (bf16_t)b.w;
    *(bf16x8*)(dst + (size_t)i * 8) = o;
    return;
  }
  bid -= 6144;
  const float* src; bf16_t* dst; int R, lb;
  if (bid < 1024)      { src = Wq; dst = WqT;                        R = 1024; lb = bid; }
  else if (bid < 3072) { src = Wk; dst = WkvT;                       R = 2048; lb = bid - 1024; }
  else if (bid < 5120) { src = Wv; dst = WkvT + (size_t)1024 * 2048; R = 2048; lb = bid - 3072; }
  else                 { src = Wo; dst = WoT;                        R = 1024; lb = bid - 5120; }
  int c0 = (lb & 31) << 5, r0 = (lb >> 5) << 5;
  int tc = threadIdx.x & 31, tr = threadIdx.x >> 5;  // tr in 0..7
#pragma unroll
  for (int i = 0; i < 4; i++)
    tile[tr + i * 8][tc] = src[(size_t)(r0 + tr + i * 8) * 1024 + c0 + tc];
  __syncthreads();
#pragma unroll
  for (int i = 0; i < 4; i++)
    dst[(size_t)(c0 + tr + i * 8) * R + r0 + tc] = (bf16_t)tile[tc][tr + i * 8];
}

// ============ shared GEMM body pieces (128x128x32, 4 waves 2x2) ============
// (round-5 verified form: 2-buffer, 1 __syncthreads per K-step, swizzled LDS)
#define GEMM_STAGE(buf, kt)                                                    \
  {                                                                            \
    const int kbase = (kt) * 32;                                               \
    int kg0 = kbase + ak0;                                                     \
    const bf16_t* s0 = (kg0 < Ksplit)                                          \
                           ? (A0 + (size_t)(m0 + ar0) * 1024 + kg0)            \
                           : (A1 + (size_t)(m0 + ar0) * 1024 + (kg0 - Ksplit));\
    GLD_LDS16(s0, As[buf] + c0 * 8);                                           \
    int kg1 = kbase + ak1;                                                     \
    const bf16_t* s1 = (kg1 < Ksplit)                                          \
                           ? (A0 + (size_t)(m0 + ar1) * 1024 + kg1)            \
                           : (A1 + (size_t)(m0 + ar1) * 1024 + (kg1 - Ksplit));\
    GLD_LDS16(s1, As[buf] + c1 * 8);                                           \
    const bf16_t* b0 = BT + (size_t)(n0 + ar0) * Ktot + kbase + ak0;           \
    GLD_LDS16(b0, Bs[buf] + c0 * 8);                                           \
    const bf16_t* b1 = BT + (size_t)(n0 + ar1) * Ktot + kbase + ak1;           \
    GLD_LDS16(b1, Bs[buf] + c1 * 8);                                           \
  }

#define GEMM_DECLS                                                             \
  const int t = threadIdx.x, w = t >> 6, l = t & 63;                           \
  const int l15 = l & 15, l4 = l >> 4;                                         \
  const int wr = w >> 1, wc = w & 1;                                           \
  const int c0 = t, c1 = t + 256;                                              \
  const int ar0 = c0 >> 2, ar1 = c1 >> 2;                                      \
  const int ak0 = ((c0 & 3) ^ ((ar0 >> 1) & 3)) * 8;                           \
  const int ak1 = ((c1 & 3) ^ ((ar1 >> 1) & 3)) * 8;                           \
  int offA[4], offB[4];                                                        \
  _Pragma("unroll") for (int mi = 0; mi < 4; mi++) {                           \
    int rA = wr * 64 + mi * 16 + l15;                                          \
    offA[mi] = rA * 32 + (l4 ^ ((rA >> 1) & 3)) * 8;                           \
    int rB = wc * 64 + mi * 16 + l15;                                          \
    offB[mi] = rB * 32 + (l4 ^ ((rB >> 1) & 3)) * 8;                           \
  }

#define GEMM_MAINLOOP                                                          \
  GEMM_STAGE(0, 0);                                                            \
  __syncthreads();                                                             \
  int cur = 0;                                                                 \
  for (int kt = 0; kt < nkt; ++kt) {                                           \
    if (kt + 1 < nkt) GEMM_STAGE(cur ^ 1, kt + 1);                             \
    bf16x8 af[4], bfr[4];                                                      \
    _Pragma("unroll") for (int mi = 0; mi < 4; mi++)                           \
        af[mi] = *(const bf16x8*)&As[cur][offA[mi]];                           \
    _Pragma("unroll") for (int ni = 0; ni < 4; ni++)                           \
        bfr[ni] = *(const bf16x8*)&Bs[cur][offB[ni]];                          \
    _Pragma("unroll") for (int mi = 0; mi < 4; mi++)                           \
        _Pragma("unroll") for (int ni = 0; ni < 4; ni++)                       \
            acc[mi][ni] = __builtin_amdgcn_mfma_f32_16x16x32_bf16(             \
                af[mi], bfr[ni], acc[mi][ni], 0, 0, 0);                        \
    __syncthreads();                                                           \
    cur ^= 1;                                                                  \
  }

// ---- fused Q-proj + KV-proj: blocks 0..255 -> Q (K=1024); 256..767 -> KV --
__global__ __launch_bounds__(256, 2) void qkv_kernel(
    const bf16_t* __restrict__ xbp, const bf16_t* __restrict__ ybp,
    const bf16_t* __restrict__ WqT, const bf16_t* __restrict__ WkvT,
    bf16_t* __restrict__ Qb, bf16_t* __restrict__ Kb,
    bf16_t* __restrict__ VTb) {
  __shared__ bf16_t As[2][128 * 32];
  __shared__ bf16_t Bs[2][128 * 32];
  GEMM_DECLS
  const bool isQ = blockIdx.x < 256;
  const int i = isQ ? blockIdx.x : blockIdx.x - 256;
  const int ybt = (i & 7) * 4 + ((i >> 3) & 3);  // A-panel per XCD
  const int xbt = i >> 5;
  const int m0 = ybt * 128, n0 = xbt * 128;
  const bf16_t* A0 = isQ ? xbp : ybp;
  const bf16_t* A1 = isQ ? xbp : ybp + (size_t)4096 * 1024;
  const int Ksplit = 1024;
  const bf16_t* BT = isQ ? WqT : WkvT;
  const int Ktot = isQ ? 1024 : 2048;
  const int nkt = Ktot >> 5;
  f32x4 acc[4][4] = {};

  GEMM_MAINLOOP

#pragma unroll
  for (int mi = 0; mi < 4; mi++) {
#pragma unroll
    for (int ni = 0; ni < 4; ni++) {
      const int rbase = m0 + wr * 64 + mi * 16 + l4 * 4;
      const int col = n0 + wc * 64 + ni * 16 + l15;
      if (isQ) {
#pragma unroll
        for (int rr = 0; rr < 4; rr++)
          Qb[(size_t)(rbase + rr) * 1024 + col] =
              (bf16_t)(acc[mi][ni][rr] * (0.125f * LOG2E));
      } else if (n0 < 1024) {
#pragma unroll
        for (int rr = 0; rr < 4; rr++)
          Kb[(size_t)(rbase + rr) * 1024 + col] = (bf16_t)acc[mi][ni][rr];
      } else {
        union { unsigned short u[4]; uint2 v; } pk;
#pragma unroll
        for (int rr = 0; rr < 4; rr++)
          pk.u[rr] = bf16_bits(acc[mi][ni][rr]);
        *(uint2*)&VTb[(size_t)(col - 1024) * 4096 + rbase] = pk.v;
      }
    }
  }
}

// ---- O-proj: out(fp32) = ctx * WoT^T ---------------------------------------
__global__ __launch_bounds__(256, 2) void gemm_o(const bf16_t* __restrict__ A0,
                                                 const bf16_t* __restrict__ BT,
                                                 float* __restrict__ Cp) {
  __shared__ bf16_t As[2][128 * 32];
  __shared__ bf16_t Bs[2][128 * 32];
  GEMM_DECLS
  const int i = blockIdx.x;
  const int ybt = (i & 7) * 4 + ((i >> 3) & 3);
  const int xbt = i >> 5;
  const int m0 = ybt * 128, n0 = xbt * 128;
  const bf16_t* A1 = A0;
  const int Ksplit = 1024, Ktot = 1024, nkt = 32;
  f32x4 acc[4][4] = {};

  GEMM_MAINLOOP

#pragma unroll
  for (int mi = 0; mi < 4; mi++) {
#pragma unroll
    for (int ni = 0; ni < 4; ni++) {
      const int rbase = m0 + wr * 64 + mi * 16 + l4 * 4;
      const int col = n0 + wc * 64 + ni * 16 + l15;
#pragma unroll
      for (int rr = 0; rr < 4; rr++)
        Cp[(size_t)(rbase + rr) * 1024 + col] = acc[mi][ni][rr];
    }
  }
}

// ---------------- flash attention, 32x32 MFMA + register-P ------------------
// 512 blocks (qt 0..7, bh 0..63; bh = id&63 keeps one (b,h)'s 8 blocks on one
// XCD). 4 waves x 32 q-rows = QB=128, KB=64. S^T = mfma32(K,Q): lane holds 32
// of 64 keys for q = lane&31 (other half in lane^32). Softmax register-local;
// P -> PV B-operand entirely in registers via v_cvt_pk_bf16_f32 +
// v_permlane32_swap_b32 (T12). LDS: only K/V tiles (double-buffered,
// XOR-swizzled). Per iter per wave: 16 b128 LDS reads, 16 mfma32, 0 P-LDS.
__global__ __launch_bounds__(256, 2) void attn_kernel(
    const bf16_t* __restrict__ Q, const bf16_t* __restrict__ K,
    const bf16_t* __restrict__ VT, const float* __restrict__ bias,
    bf16_t* __restrict__ ctx) {
  __shared__ bf16_t Ks[2][64 * 64];
  __shared__ bf16_t Vs[2][64 * 64];
  const int t = threadIdx.x, w = t >> 6, l = t & 63;
  const int l31 = l & 31, hi = l >> 5;
  const int id = blockIdx.x;
  const int bh = id & 63, qt = id >> 6;  // qt 0..7
  const int b = bh >> 4, h = bh & 15;
  const int q_local = w * 32 + l31;  // 0..127

  // Q as B-operand of 32x32x16: col=q=lane&31, k = hi*8+j within 16-slice
  bf16x8 qf[4];
  {
    const bf16_t* Qp =
        Q + (size_t)(b * 1024 + qt * 128 + q_local) * 1024 + h * 64 + hi * 8;
#pragma unroll
    for (int ds = 0; ds < 4; ds++) qf[ds] = *(const bf16x8*)&Qp[ds * 16];
  }

#define ATTN_STAGE(buf, kt)                                                    \
  {                                                                            \
    _Pragma("unroll") for (int j = 0; j < 2; j++) {                            \
      int c = t + j * 256;                                                     \
      int row = c >> 3, sl = (c & 7) ^ (row & 7);                              \
      const bf16_t* srck =                                                     \
          K + (size_t)(b * 1024 + (kt) * 64 + row) * 1024 + h * 64 + sl * 8;   \
      GLD_LDS16(srck, Ks[buf] + c * 8);                                        \
      const bf16_t* srcv =                                                     \
          VT + (size_t)(h * 64 + row) * 4096 + b * 1024 + (kt) * 64 + sl * 8;  \
      GLD_LDS16(srcv, Vs[buf] + c * 8);                                        \
    }                                                                          \
  }

  float mrun = -INFINITY, lrun = 0.f;
  f32x16 cacc[2] = {};  // ctx^T: d = dg*32 + (r&3)+8*(r>>2)+4*hi, q = l31

  ATTN_STAGE(0, 0);
  __syncthreads();
  int cur = 0;
  for (int kt = 0; kt < 16; ++kt) {
    if (kt + 1 < 16) ATTN_STAGE(cur ^ 1, kt + 1);

    // S^T[key][q]: sacc[kg], key = kg*32 + (r&3)+8*(r>>2)+4*hi, q = l31
    f32x16 sacc[2] = {};
#pragma unroll
    for (int ds = 0; ds < 4; ds++) {
#pragma unroll
      for (int kg = 0; kg < 2; kg++) {
        int krow = kg * 32 + l31;
        int eoff = (krow * 64 + ds * 16 + hi * 8) ^ ((krow & 7) << 3);
        bf16x8 kf = *(const bf16x8*)&Ks[cur][eoff];
        sacc[kg] = __builtin_amdgcn_mfma_f32_32x32x16_bf16(kf, qf[ds],
                                                           sacc[kg], 0, 0, 0);
      }
    }
    // + bias*2*log2e per key (fmac with broadcast float4 loads)
#pragma unroll
    for (int kg = 0; kg < 2; kg++) {
#pragma unroll
      for (int mm = 0; mm < 4; mm++) {
        f32x4 bb = *(const f32x4*)&bias[b * 1024 + kt * 64 + kg * 32 + mm * 8 +
                                        hi * 4];
#pragma unroll
        for (int rr = 0; rr < 4; rr++)
          sacc[kg][mm * 4 + rr] += (2.0f * LOG2E) * bb[rr];
      }
    }
    // softmax: 32 keys in-lane + partner half via shfl_xor(32)
    float tm = -INFINITY;
#pragma unroll
    for (int kg = 0; kg < 2; kg++)
#pragma unroll
      for (int r = 0; r < 16; r++) tm = fmaxf(tm, sacc[kg][r]);
    tm = fmaxf(tm, __shfl_xor(tm, 32));
    float mnew = fmaxf(mrun, tm);
    float sc = exp2f(mrun - mnew);
    float rsum = 0.f;
#pragma unroll
    for (int kg = 0; kg < 2; kg++)
#pragma unroll
      for (int r = 0; r < 16; r++) {
        float p = exp2f(sacc[kg][r] - mnew);
        sacc[kg][r] = p;
        rsum += p;
      }
    rsum += __shfl_xor(rsum, 32);
    lrun = lrun * sc + rsum;
    mrun = mnew;
#pragma unroll
    for (int dg = 0; dg < 2; dg++)
#pragma unroll
      for (int r = 0; r < 16; r++) cacc[dg][r] *= sc;

    // pack P -> PV B-fragments in registers (cvt_pk + permlane32_swap)
    bf16x8 pb[4];
#pragma unroll
    for (int kg = 0; kg < 2; kg++) {
#pragma unroll
      for (int tt = 0; tt < 2; tt++) {
        uint32_t w0A, w1A, w0B, w1B;
        const int mA = 2 * tt, mB = 2 * tt + 1;
        asm("v_cvt_pk_bf16_f32 %0, %1, %2"
            : "=v"(w0A)
            : "v"(sacc[kg][4 * mA + 0]), "v"(sacc[kg][4 * mA + 1]));
        asm("v_cvt_pk_bf16_f32 %0, %1, %2"
            : "=v"(w1A)
            : "v"(sacc[kg][4 * mA + 2]), "v"(sacc[kg][4 * mA + 3]));
        asm("v_cvt_pk_bf16_f32 %0, %1, %2"
            : "=v"(w0B)
            : "v"(sacc[kg][4 * mB + 0]), "v"(sacc[kg][4 * mB + 1]));
        asm("v_cvt_pk_bf16_f32 %0, %1, %2"
            : "=v"(w1B)
            : "v"(sacc[kg][4 * mB + 2]), "v"(sacc[kg][4 * mB + 3]));
        asm("v_permlane32_swap_b32 %0, %1" : "+v"(w0A), "+v"(w0B));
        asm("v_permlane32_swap_b32 %0, %1" : "+v"(w1A), "+v"(w1B));
        union { uint32_t u[4]; bf16x8 v; } pk;
        pk.u[0] = w0A; pk.u[1] = w1A; pk.u[2] = w0B; pk.u[3] = w1B;
        pb[kg * 2 + tt] = pk.v;
      }
    }
    // PV: ctx^T = mfma32(A = V^T[d][k] from LDS, B = P^T[k][q] regs)
#pragma unroll
    for (int dg = 0; dg < 2; dg++) {
#pragma unroll
      for (int k4 = 0; k4 < 4; k4++) {
        int vrow = dg * 32 + l31;
        int eoff = (vrow * 64 + k4 * 16 + hi * 8) ^ ((vrow & 7) << 3);
        bf16x8 vf = *(const bf16x8*)&Vs[cur][eoff];
        cacc[dg] = __builtin_amdgcn_mfma_f32_32x32x16_bf16(vf, pb[k4],
                                                           cacc[dg], 0, 0, 0);
      }
    }
    __syncthreads();
    cur ^= 1;
  }

  // epilogue: ctx^T -> LDS transpose (swizzled, 128q x 64d over Ks) -> stores
  bf16_t* T = (bf16_t*)Ks;  // 16KB
  {
    float inv = 1.0f / lrun;
#pragma unroll
    for (int dg = 0; dg < 2; dg++) {
#pragma unroll
      for (int m = 0; m < 4; m++) {
        bf16x4 tv;
#pragma unroll
        for (int rr = 0; rr < 4; rr++)
          tv[rr] = (bf16_t)(cacc[dg][4 * m + rr] * inv);
        int d0 = dg * 32 + m * 8 + hi * 4;
        *(bf16x4*)&T[q_local * 64 + (d0 ^ ((q_local & 7) << 3))] = tv;
      }
    }
  }
  __syncthreads();
#pragma unroll
  for (int c = t; c < 1024; c += 256) {
    int row = c >> 3, col8 = c & 7;
    bf16x8 v = *(const bf16x8*)&T[row * 64 + ((col8 * 8) ^ ((row & 7) << 3))];
    *(bf16x8*)&ctx[(size_t)(b * 1024 + qt * 128 + row) * 1024 + h * 64 +
                   col8 * 8] = v;
  }
#undef ATTN_STAGE
}

extern "C" void kernel_launch(void* const* d_in, const int* in_sizes, int n_in,
                              void* d_out, int out_size, void* d_ws,
                              size_t ws_size, hipStream_t stream) {
  const float* x = (const float*)d_in[0];    // [4,1024,1024]
  const float* y = (const float*)d_in[1];    // [2,4,1024,1024]
  const float* bias = (const float*)d_in[2]; // [4,1,1,1024]
  const float* Wq = (const float*)d_in[3];   // [1024,1024]
  const float* Wk = (const float*)d_in[4];   // [2,1024,1024]
  const float* Wv = (const float*)d_in[5];
  const float* Wo = (const float*)d_in[6];
  float* out = (float*)d_out;                // [4,1024,1024] fp32

  char* ws = (char*)d_ws;
  const size_t MB = 1024 * 1024;
  bf16_t* xb   = (bf16_t*)(ws + 0 * MB);    // 8MB
  bf16_t* yb   = (bf16_t*)(ws + 8 * MB);    // 16MB
  bf16_t* WqT  = (bf16_t*)(ws + 24 * MB);   // 2MB
  bf16_t* WkvT = (bf16_t*)(ws + 26 * MB);   // 8MB  [2048 n][2048 k]
  bf16_t* WoT  = (bf16_t*)(ws + 34 * MB);   // 2MB
  bf16_t* Qb   = (bf16_t*)(ws + 36 * MB);   // 8MB  (pre-scaled d^-.5*log2e)
  bf16_t* Kb   = (bf16_t*)(ws + 44 * MB);   // 8MB
  bf16_t* VTb  = (bf16_t*)(ws + 52 * MB);   // 8MB  [1024 d][4096 q]
  bf16_t* ctxb = (bf16_t*)(ws + 60 * MB);   // 8MB

  prep_kernel<<<12288, 256, 0, stream>>>(x, y, Wq, Wk, Wv, Wo, xb, yb, WqT,
                                         WkvT, WoT);
  // Q-proj (blocks 0..255) + KV-proj (blocks 256..767), fused, 128^2 tiles
  qkv_kernel<<<768, 256, 0, stream>>>(xb, yb, WqT, WkvT, Qb, Kb, VTb);
  attn_kernel<<<512, 256, 0, stream>>>(Qb, Kb, VTb, bias, ctxb);
  gemm_o<<<256, 256, 0, stream>>>(ctxb, WoT, out);
}

// Round 9
// 134.260 us; speedup vs baseline: 1.2090x; 1.0544x over previous
//
#include <hip/hip_runtime.h>
#include <cstdint>

typedef __bf16 bf16_t;
typedef bf16_t bf16x4 __attribute__((ext_vector_type(4)));
typedef bf16_t bf16x8 __attribute__((ext_vector_type(8)));
typedef float f32x4 __attribute__((ext_vector_type(4)));
typedef float f32x16 __attribute__((ext_vector_type(16)));

#define GLD_LDS16(g, l)                                                        \
  __builtin_amdgcn_global_load_lds(                                            \
      (const __attribute__((address_space(1))) void*)(g),                      \
      (__attribute__((address_space(3))) void*)(l), 16, 0, 0)

#define LOG2E 1.44269504088896340736f

static __device__ __forceinline__ unsigned short bf16_bits(float f) {
  bf16_t h = (bf16_t)f;
  return __builtin_bit_cast(unsigned short, h);
}

// ---- fused prep: fp32->bf16 convert (x,y) + weight transpose-convert ------
__global__ void prep_kernel(const float* __restrict__ x,
                            const float* __restrict__ y,
                            const float* __restrict__ Wq,
                            const float* __restrict__ Wk,
                            const float* __restrict__ Wv,
                            const float* __restrict__ Wo,
                            bf16_t* __restrict__ xb, bf16_t* __restrict__ yb,
                            bf16_t* __restrict__ WqT,
                            bf16_t* __restrict__ WkvT,
                            bf16_t* __restrict__ WoT) {
  __shared__ float tile[32][33];
  int bid = blockIdx.x;
  if (bid < 6144) {
    int i = bid * 256 + threadIdx.x;
    const float* src;
    bf16_t* dst;
    if (i < 524288) { src = x; dst = xb; }
    else            { src = y; dst = yb; i -= 524288; }
    const float4* s = (const float4*)src;
    float4 a = s[i * 2];
    float4 b = s[i * 2 + 1];
    bf16x8 o;
    o[0] = (bf16_t)a.x; o[1] = (bf16_t)a.y; o[2] = (bf16_t)a.z; o[3] = (bf16_t)a.w;
    o[4] = (bf16_t)b.x; o[5] = (bf16_t)b.y; o[6] = (bf16_t)b.z; o[7] = (bf16_t)b.w;
    *(bf16x8*)(dst + (size_t)i * 8) = o;
    return;
  }
  bid -= 6144;
  const float* src; bf16_t* dst; int R, lb;
  if (bid < 1024)      { src = Wq; dst = WqT;                        R = 1024; lb = bid; }
  else if (bid < 3072) { src = Wk; dst = WkvT;                       R = 2048; lb = bid - 1024; }
  else if (bid < 5120) { src = Wv; dst = WkvT + (size_t)1024 * 2048; R = 2048; lb = bid - 3072; }
  else                 { src = Wo; dst = WoT;                        R = 1024; lb = bid - 5120; }
  int c0 = (lb & 31) << 5, r0 = (lb >> 5) << 5;
  int tc = threadIdx.x & 31, tr = threadIdx.x >> 5;  // tr in 0..7
#pragma unroll
  for (int i = 0; i < 4; i++)
    tile[tr + i * 8][tc] = src[(size_t)(r0 + tr + i * 8) * 1024 + c0 + tc];
  __syncthreads();
#pragma unroll
  for (int i = 0; i < 4; i++)
    dst[(size_t)(c0 + tr + i * 8) * R + r0 + tc] = (bf16_t)tile[tc][tr + i * 8];
}

// ============ shared GEMM body pieces (128x128x32, 4 waves 2x2) ============
#define GEMM_STAGE(buf, kt)                                                    \
  {                                                                            \
    const int kbase = (kt) * 32;                                               \
    int kg0 = kbase + ak0;                                                     \
    const bf16_t* s0 = (kg0 < Ksplit)                                          \
                           ? (A0 + (size_t)(m0 + ar0) * 1024 + kg0)            \
                           : (A1 + (size_t)(m0 + ar0) * 1024 + (kg0 - Ksplit));\
    GLD_LDS16(s0, As[buf] + c0 * 8);                                           \
    int kg1 = kbase + ak1;                                                     \
    const bf16_t* s1 = (kg1 < Ksplit)                                          \
                           ? (A0 + (size_t)(m0 + ar1) * 1024 + kg1)            \
                           : (A1 + (size_t)(m0 + ar1) * 1024 + (kg1 - Ksplit));\
    GLD_LDS16(s1, As[buf] + c1 * 8);                                           \
    const bf16_t* b0 = BT + (size_t)(n0 + ar0) * Ktot + kbase + ak0;           \
    GLD_LDS16(b0, Bs[buf] + c0 * 8);                                           \
    const bf16_t* b1 = BT + (size_t)(n0 + ar1) * Ktot + kbase + ak1;           \
    GLD_LDS16(b1, Bs[buf] + c1 * 8);                                           \
  }

#define GEMM_DECLS                                                             \
  const int t = threadIdx.x, w = t >> 6, l = t & 63;                           \
  const int l15 = l & 15, l4 = l >> 4;                                         \
  const int wr = w >> 1, wc = w & 1;                                           \
  const int c0 = t, c1 = t + 256;                                              \
  const int ar0 = c0 >> 2, ar1 = c1 >> 2;                                      \
  const int ak0 = ((c0 & 3) ^ ((ar0 >> 1) & 3)) * 8;                           \
  const int ak1 = ((c1 & 3) ^ ((ar1 >> 1) & 3)) * 8;                           \
  int offA[4], offB[4];                                                        \
  _Pragma("unroll") for (int mi = 0; mi < 4; mi++) {                           \
    int rA = wr * 64 + mi * 16 + l15;                                          \
    offA[mi] = rA * 32 + (l4 ^ ((rA >> 1) & 3)) * 8;                           \
    int rB = wc * 64 + mi * 16 + l15;                                          \
    offB[mi] = rB * 32 + (l4 ^ ((rB >> 1) & 3)) * 8;                           \
  }

#define GEMM_MAINLOOP                                                          \
  GEMM_STAGE(0, 0);                                                            \
  __syncthreads();                                                             \
  int cur = 0;                                                                 \
  for (int kt = 0; kt < nkt; ++kt) {                                           \
    if (kt + 1 < nkt) GEMM_STAGE(cur ^ 1, kt + 1);                             \
    bf16x8 af[4], bfr[4];                                                      \
    _Pragma("unroll") for (int mi = 0; mi < 4; mi++)                           \
        af[mi] = *(const bf16x8*)&As[cur][offA[mi]];                           \
    _Pragma("unroll") for (int ni = 0; ni < 4; ni++)                           \
        bfr[ni] = *(const bf16x8*)&Bs[cur][offB[ni]];                          \
    _Pragma("unroll") for (int mi = 0; mi < 4; mi++)                           \
        _Pragma("unroll") for (int ni = 0; ni < 4; ni++)                       \
            acc[mi][ni] = __builtin_amdgcn_mfma_f32_16x16x32_bf16(             \
                af[mi], bfr[ni], acc[mi][ni], 0, 0, 0);                        \
    __syncthreads();                                                           \
    cur ^= 1;                                                                  \
  }

// ---- fused Q-proj + KV-proj: blocks 0..255 -> Q (K=1024); 256..767 -> KV --
__global__ __launch_bounds__(256, 2) void qkv_kernel(
    const bf16_t* __restrict__ xbp, const bf16_t* __restrict__ ybp,
    const bf16_t* __restrict__ WqT, const bf16_t* __restrict__ WkvT,
    bf16_t* __restrict__ Qb, bf16_t* __restrict__ Kb,
    bf16_t* __restrict__ VTb) {
  __shared__ bf16_t As[2][128 * 32];
  __shared__ bf16_t Bs[2][128 * 32];
  GEMM_DECLS
  const bool isQ = blockIdx.x < 256;
  const int i = isQ ? blockIdx.x : blockIdx.x - 256;
  const int ybt = (i & 7) * 4 + ((i >> 3) & 3);  // A-panel per XCD
  const int xbt = i >> 5;
  const int m0 = ybt * 128, n0 = xbt * 128;
  const bf16_t* A0 = isQ ? xbp : ybp;
  const bf16_t* A1 = isQ ? xbp : ybp + (size_t)4096 * 1024;
  const int Ksplit = 1024;
  const bf16_t* BT = isQ ? WqT : WkvT;
  const int Ktot = isQ ? 1024 : 2048;
  const int nkt = Ktot >> 5;
  f32x4 acc[4][4] = {};

  GEMM_MAINLOOP

#pragma unroll
  for (int mi = 0; mi < 4; mi++) {
#pragma unroll
    for (int ni = 0; ni < 4; ni++) {
      const int rbase = m0 + wr * 64 + mi * 16 + l4 * 4;
      const int col = n0 + wc * 64 + ni * 16 + l15;
      if (isQ) {
#pragma unroll
        for (int rr = 0; rr < 4; rr++)
          Qb[(size_t)(rbase + rr) * 1024 + col] =
              (bf16_t)(acc[mi][ni][rr] * (0.125f * LOG2E));
      } else if (n0 < 1024) {
#pragma unroll
        for (int rr = 0; rr < 4; rr++)
          Kb[(size_t)(rbase + rr) * 1024 + col] = (bf16_t)acc[mi][ni][rr];
      } else {
        union { unsigned short u[4]; uint2 v; } pk;
#pragma unroll
        for (int rr = 0; rr < 4; rr++)
          pk.u[rr] = bf16_bits(acc[mi][ni][rr]);
        *(uint2*)&VTb[(size_t)(col - 1024) * 4096 + rbase] = pk.v;
      }
    }
  }
}

// ---- O-proj: out(fp32) = ctx * WoT^T. 128x64 tiles -> 512 blocks (2/CU) ---
__global__ __launch_bounds__(256, 2) void gemm_o(const bf16_t* __restrict__ A0,
                                                 const bf16_t* __restrict__ BT,
                                                 float* __restrict__ Cp) {
  __shared__ bf16_t As[2][128 * 32];
  __shared__ bf16_t Bs[2][64 * 32];
  const int t = threadIdx.x, w = t >> 6, l = t & 63;
  const int l15 = l & 15, l4 = l >> 4;
  const int wr = w >> 1, wc = w & 1;
  const int c0 = t, c1 = t + 256, c2 = t;  // A: 512 chunks; B: 256 chunks
  const int ar0 = c0 >> 2, ar1 = c1 >> 2, br2 = c2 >> 2;
  const int ak0 = ((c0 & 3) ^ ((ar0 >> 1) & 3)) * 8;
  const int ak1 = ((c1 & 3) ^ ((ar1 >> 1) & 3)) * 8;
  const int bk2 = ((c2 & 3) ^ ((br2 >> 1) & 3)) * 8;
  int offA[4], offB[2];
#pragma unroll
  for (int mi = 0; mi < 4; mi++) {
    int rA = wr * 64 + mi * 16 + l15;
    offA[mi] = rA * 32 + (l4 ^ ((rA >> 1) & 3)) * 8;
  }
#pragma unroll
  for (int ni = 0; ni < 2; ni++) {
    int rB = wc * 32 + ni * 16 + l15;
    offB[ni] = rB * 32 + (l4 ^ ((rB >> 1) & 3)) * 8;
  }
  const int i = blockIdx.x;
  const int ybt = (i & 7) * 4 + ((i >> 3) & 3);  // A-panel per XCD (32 m)
  const int xbt = i >> 5;                        // 16 n-tiles of 64
  const int m0 = ybt * 128, n0 = xbt * 64;
  const int nkt = 32;
  f32x4 acc[4][2] = {};

#define OST(buf, kt)                                                           \
  {                                                                            \
    const int kbase = (kt) * 32;                                               \
    const bf16_t* s0 = A0 + (size_t)(m0 + ar0) * 1024 + kbase + ak0;           \
    GLD_LDS16(s0, As[buf] + c0 * 8);                                           \
    const bf16_t* s1 = A0 + (size_t)(m0 + ar1) * 1024 + kbase + ak1;           \
    GLD_LDS16(s1, As[buf] + c1 * 8);                                           \
    const bf16_t* b0 = BT + (size_t)(n0 + br2) * 1024 + kbase + bk2;           \
    GLD_LDS16(b0, Bs[buf] + c2 * 8);                                           \
  }

  OST(0, 0);
  __syncthreads();
  int cur = 0;
  for (int kt = 0; kt < nkt; ++kt) {
    if (kt + 1 < nkt) OST(cur ^ 1, kt + 1);
    bf16x8 af[4], bfr[2];
#pragma unroll
    for (int mi = 0; mi < 4; mi++)
      af[mi] = *(const bf16x8*)&As[cur][offA[mi]];
#pragma unroll
    for (int ni = 0; ni < 2; ni++)
      bfr[ni] = *(const bf16x8*)&Bs[cur][offB[ni]];
#pragma unroll
    for (int mi = 0; mi < 4; mi++)
#pragma unroll
      for (int ni = 0; ni < 2; ni++)
        acc[mi][ni] = __builtin_amdgcn_mfma_f32_16x16x32_bf16(
            af[mi], bfr[ni], acc[mi][ni], 0, 0, 0);
    __syncthreads();
    cur ^= 1;
  }
#undef OST

#pragma unroll
  for (int mi = 0; mi < 4; mi++) {
#pragma unroll
    for (int ni = 0; ni < 2; ni++) {
      const int rbase = m0 + wr * 64 + mi * 16 + l4 * 4;
      const int col = n0 + wc * 32 + ni * 16 + l15;
#pragma unroll
      for (int rr = 0; rr < 4; rr++)
        Cp[(size_t)(rbase + rr) * 1024 + col] = acc[mi][ni][rr];
    }
  }
}

// ---------------- flash attention, 32x32 MFMA + register-P, KB=128 ---------
// 512 blocks (qt 0..7, bh = id&63 -> one (b,h)'s 8 blocks share an XCD).
// 4 waves x 32 q-rows = QB=128. Staged K-tile = 128 keys (32KB K+V, dbuf,
// 64KB LDS total); each tile processed as two 64-key online-softmax halves.
// 8 outer iterations -> half the barrier+vmcnt-drain events of KB=64.
__global__ __launch_bounds__(256, 2) void attn_kernel(
    const bf16_t* __restrict__ Q, const bf16_t* __restrict__ K,
    const bf16_t* __restrict__ VT, const float* __restrict__ bias,
    bf16_t* __restrict__ ctx) {
  __shared__ bf16_t Ks[2][128 * 64];  // [key][d], 128B rows, ^(row&7) swizzle
  __shared__ bf16_t Vs[2][64 * 128];  // [d][key], 256B rows, ^((row&7)<<1)
  const int t = threadIdx.x, w = t >> 6, l = t & 63;
  const int l31 = l & 31, hi = l >> 5;
  const int id = blockIdx.x;
  const int bh = id & 63, qt = id >> 6;  // qt 0..7
  const int b = bh >> 4, h = bh & 15;
  const int q_local = w * 32 + l31;  // 0..127

  // Q as B-operand of 32x32x16: col=q=lane&31, k = hi*8+j within 16-slice
  bf16x8 qf[4];
  {
    const bf16_t* Qp =
        Q + (size_t)(b * 1024 + qt * 128 + q_local) * 1024 + h * 64 + hi * 8;
#pragma unroll
    for (int ds = 0; ds < 4; ds++) qf[ds] = *(const bf16x8*)&Qp[ds * 16];
  }

  // stage: K tile 2048 chunks (8/thread? no: 128*64*2B/16B = 1024 chunks),
  // V tile 1024 chunks; 4 j-iters each.
#define ATTN_STAGE(buf, kt)                                                    \
  {                                                                            \
    _Pragma("unroll") for (int j = 0; j < 4; j++) {                            \
      int c = t + j * 256;                                                     \
      int rowk = c >> 3, slk = (c & 7) ^ (rowk & 7);                           \
      const bf16_t* srck =                                                     \
          K + (size_t)(b * 1024 + (kt) * 128 + rowk) * 1024 + h * 64 + slk * 8;\
      GLD_LDS16(srck, Ks[buf] + c * 8);                                        \
      int rowv = c >> 4, slv = (c & 15) ^ ((rowv & 7) << 1);                   \
      const bf16_t* srcv =                                                     \
          VT + (size_t)(h * 64 + rowv) * 4096 + b * 1024 + (kt) * 128 +        \
          slv * 8;                                                             \
      GLD_LDS16(srcv, Vs[buf] + c * 8);                                        \
    }                                                                          \
  }

  float mrun = -INFINITY, lrun = 0.f;
  f32x16 cacc[2] = {};  // ctx^T: d = dg*32 + (r&3)+8*(r>>2)+4*hi, q = l31

  ATTN_STAGE(0, 0);
  __syncthreads();
  int cur = 0;
  for (int kts = 0; kts < 8; ++kts) {
    if (kts + 1 < 8) ATTN_STAGE(cur ^ 1, kts + 1);

#pragma unroll
    for (int half = 0; half < 2; ++half) {
      // S^T[key][q]: sacc[kg], key = half*64 + kg*32 + (r&3)+8*(r>>2)+4*hi
      f32x16 sacc[2] = {};
#pragma unroll
      for (int ds = 0; ds < 4; ds++) {
#pragma unroll
        for (int kg = 0; kg < 2; kg++) {
          int krow = half * 64 + kg * 32 + l31;
          int eoff = krow * 64 + (((ds * 2 + hi) ^ (krow & 7)) * 8);
          bf16x8 kf = *(const bf16x8*)&Ks[cur][eoff];
          sacc[kg] = __builtin_amdgcn_mfma_f32_32x32x16_bf16(
              kf, qf[ds], sacc[kg], 0, 0, 0);
        }
      }
      // + bias*2*log2e per key
#pragma unroll
      for (int kg = 0; kg < 2; kg++) {
#pragma unroll
        for (int mm = 0; mm < 4; mm++) {
          f32x4 bb = *(const f32x4*)&bias[b * 1024 + kts * 128 + half * 64 +
                                          kg * 32 + mm * 8 + hi * 4];
#pragma unroll
          for (int rr = 0; rr < 4; rr++)
            sacc[kg][mm * 4 + rr] += (2.0f * LOG2E) * bb[rr];
        }
      }
      // softmax: 32 keys in-lane + partner half via shfl_xor(32)
      float tm = -INFINITY;
#pragma unroll
      for (int kg = 0; kg < 2; kg++)
#pragma unroll
        for (int r = 0; r < 16; r++) tm = fmaxf(tm, sacc[kg][r]);
      tm = fmaxf(tm, __shfl_xor(tm, 32));
      float mnew = fmaxf(mrun, tm);
      float sc = exp2f(mrun - mnew);
      float rsum = 0.f;
#pragma unroll
      for (int kg = 0; kg < 2; kg++)
#pragma unroll
        for (int r = 0; r < 16; r++) {
          float p = exp2f(sacc[kg][r] - mnew);
          sacc[kg][r] = p;
          rsum += p;
        }
      rsum += __shfl_xor(rsum, 32);
      lrun = lrun * sc + rsum;
      mrun = mnew;
#pragma unroll
      for (int dg = 0; dg < 2; dg++)
#pragma unroll
        for (int r = 0; r < 16; r++) cacc[dg][r] *= sc;

      // pack P -> PV B-fragments in registers (cvt_pk + permlane32_swap)
      bf16x8 pb[4];
#pragma unroll
      for (int kg = 0; kg < 2; kg++) {
#pragma unroll
        for (int tt = 0; tt < 2; tt++) {
          uint32_t w0A, w1A, w0B, w1B;
          const int mA = 2 * tt, mB = 2 * tt + 1;
          asm("v_cvt_pk_bf16_f32 %0, %1, %2"
              : "=v"(w0A)
              : "v"(sacc[kg][4 * mA + 0]), "v"(sacc[kg][4 * mA + 1]));
          asm("v_cvt_pk_bf16_f32 %0, %1, %2"
              : "=v"(w1A)
              : "v"(sacc[kg][4 * mA + 2]), "v"(sacc[kg][4 * mA + 3]));
          asm("v_cvt_pk_bf16_f32 %0, %1, %2"
              : "=v"(w0B)
              : "v"(sacc[kg][4 * mB + 0]), "v"(sacc[kg][4 * mB + 1]));
          asm("v_cvt_pk_bf16_f32 %0, %1, %2"
              : "=v"(w1B)
              : "v"(sacc[kg][4 * mB + 2]), "v"(sacc[kg][4 * mB + 3]));
          asm("v_permlane32_swap_b32 %0, %1" : "+v"(w0A), "+v"(w0B));
          asm("v_permlane32_swap_b32 %0, %1" : "+v"(w1A), "+v"(w1B));
          union { uint32_t u[4]; bf16x8 v; } pk;
          pk.u[0] = w0A; pk.u[1] = w1A; pk.u[2] = w0B; pk.u[3] = w1B;
          pb[kg * 2 + tt] = pk.v;
        }
      }
      // PV: ctx^T = mfma32(A = V^T[d][k] from LDS, B = P^T[k][q] regs)
#pragma unroll
      for (int dg = 0; dg < 2; dg++) {
#pragma unroll
        for (int k4 = 0; k4 < 4; k4++) {
          int vrow = dg * 32 + l31;
          int s = half * 8 + k4 * 2 + hi;
          int eoff = vrow * 128 + ((s ^ ((vrow & 7) << 1)) * 8);
          bf16x8 vf = *(const bf16x8*)&Vs[cur][eoff];
          cacc[dg] = __builtin_amdgcn_mfma_f32_32x32x16_bf16(
              vf, pb[k4], cacc[dg], 0, 0, 0);
        }
      }
    }
    __syncthreads();
    cur ^= 1;
  }

  // epilogue: ctx^T -> LDS transpose (swizzled, 128q x 64d over Ks[0]) ------
  bf16_t* T = (bf16_t*)Ks;  // 16KB
  {
    float inv = 1.0f / lrun;
#pragma unroll
    for (int dg = 0; dg < 2; dg++) {
#pragma unroll
      for (int m = 0; m < 4; m++) {
        bf16x4 tv;
#pragma unroll
        for (int rr = 0; rr < 4; rr++)
          tv[rr] = (bf16_t)(cacc[dg][4 * m + rr] * inv);
        int d0 = dg * 32 + m * 8 + hi * 4;
        *(bf16x4*)&T[q_local * 64 + (d0 ^ ((q_local & 7) << 3))] = tv;
      }
    }
  }
  __syncthreads();
#pragma unroll
  for (int c = t; c < 1024; c += 256) {
    int row = c >> 3, col8 = c & 7;
    bf16x8 v = *(const bf16x8*)&T[row * 64 + ((col8 * 8) ^ ((row & 7) << 3))];
    *(bf16x8*)&ctx[(size_t)(b * 1024 + qt * 128 + row) * 1024 + h * 64 +
                   col8 * 8] = v;
  }
#undef ATTN_STAGE
}

extern "C" void kernel_launch(void* const* d_in, const int* in_sizes, int n_in,
                              void* d_out, int out_size, void* d_ws,
                              size_t ws_size, hipStream_t stream) {
  const float* x = (const float*)d_in[0];    // [4,1024,1024]
  const float* y = (const float*)d_in[1];    // [2,4,1024,1024]
  const float* bias = (const float*)d_in[2]; // [4,1,1,1024]
  const float* Wq = (const float*)d_in[3];   // [1024,1024]
  const float* Wk = (const float*)d_in[4];   // [2,1024,1024]
  const float* Wv = (const float*)d_in[5];
  const float* Wo = (const float*)d_in[6];
  float* out = (float*)d_out;                // [4,1024,1024] fp32

  char* ws = (char*)d_ws;
  const size_t MB = 1024 * 1024;
  bf16_t* xb   = (bf16_t*)(ws + 0 * MB);    // 8MB
  bf16_t* yb   = (bf16_t*)(ws + 8 * MB);    // 16MB
  bf16_t* WqT  = (bf16_t*)(ws + 24 * MB);   // 2MB
  bf16_t* WkvT = (bf16_t*)(ws + 26 * MB);   // 8MB  [2048 n][2048 k]
  bf16_t* WoT  = (bf16_t*)(ws + 34 * MB);   // 2MB
  bf16_t* Qb   = (bf16_t*)(ws + 36 * MB);   // 8MB  (pre-scaled d^-.5*log2e)
  bf16_t* Kb   = (bf16_t*)(ws + 44 * MB);   // 8MB
  bf16_t* VTb  = (bf16_t*)(ws + 52 * MB);   // 8MB  [1024 d][4096 q]
  bf16_t* ctxb = (bf16_t*)(ws + 60 * MB);   // 8MB

  prep_kernel<<<12288, 256, 0, stream>>>(x, y, Wq, Wk, Wv, Wo, xb, yb, WqT,
                                         WkvT, WoT);
  // Q-proj (blocks 0..255) + KV-proj (blocks 256..767), fused, 128^2 tiles
  qkv_kernel<<<768, 256, 0, stream>>>(xb, yb, WqT, WkvT, Qb, Kb, VTb);
  attn_kernel<<<512, 256, 0, stream>>>(Qb, Kb, VTb, bias, ctxb);
  gemm_o<<<512, 256, 0, stream>>>(ctxb, WoT, out);
}